// Round 4
// baseline (656.386 us; speedup 1.0000x reference)
//
#include <hip/hip_runtime.h>

#define NENT 100000
#define DIM 200
#define ODIM 2000
#define KERN 9
#define OCH 32
#define LOUT 1992
#define FCLEN 63744
#define BSZ 512
#define EPSV 1e-5f
#define KPAD 224
#define NZ 64
#define NKB 1992  // FCLEN / 32 k-blocks
#define EROWS 100096  // 391 * 256, Ebf rows padded (zeros past NENT)

typedef float f32x4 __attribute__((ext_vector_type(4)));
typedef short short8 __attribute__((ext_vector_type(8)));
typedef __bf16 bf16x8 __attribute__((ext_vector_type(8)));
typedef unsigned int uint4v __attribute__((ext_vector_type(4)));
typedef unsigned int uint2v __attribute__((ext_vector_type(2)));

__device__ __forceinline__ unsigned short f2bf(float f) {
  unsigned int u = __float_as_uint(f);
  return (unsigned short)((u + 0x7fffu + ((u >> 16) & 1u)) >> 16);
}

__device__ __forceinline__ float wredf(float v) {
#pragma unroll
  for (int o = 32; o > 0; o >>= 1) v += __shfl_down(v, o, 64);
  return v;
}

// ---------- DIAGNOSTIC: fill-pattern write of d_out ----------
// 800 blocks x 256 KB contiguous slabs, plain dwordx4 stores, mimicking
// __amd_rocclr_fillBufferAligned (6.7 TB/s on d_ws). Binary readout:
// fast (~32us, below top-5 cut) => d_out is normal memory, write-path
// theory for gemmf's invariant ~120us is dead. Slow (>100us, in top-5)
// => d_out is slow-path memory, gemmf is at an external roofline.
__global__ void __launch_bounds__(256) k_probe(float* __restrict__ out) {
  const f32x4 v = (f32x4){0.5f, 0.5f, 0.5f, 0.5f};
  long base = (long)blockIdx.x * 16384 + threadIdx.x;
#pragma unroll
  for (int i = 0; i < 64; i++) {
    long idx = base + i * 256;
    if (idx < 12800000L) *(f32x4*)&out[idx * 4] = v;
  }
}

// ---------- E fp32 -> Ebf bf16 [EROWS][KPAD], zero-padded K and rows ----------
__global__ void __launch_bounds__(256) k_ebf(const float* __restrict__ E,
                                             unsigned short* __restrict__ Ebf) {
  long idx = (long)blockIdx.x * 256 + threadIdx.x;  // EROWS*56 total
  int row = (int)(idx / 56), c4 = (int)(idx % 56);
  f32x4 v = (f32x4){0.f, 0.f, 0.f, 0.f};
  if (row < NENT && c4 < 50) v = *(const f32x4*)&E[(long)row * DIM + c4 * 4];
  uint2v pk;
  pk[0] = (unsigned)f2bf(v[0]) | ((unsigned)f2bf(v[1]) << 16);
  pk[1] = (unsigned)f2bf(v[2]) | ((unsigned)f2bf(v[3]) << 16);
  *(uint2v*)&Ebf[(long)row * KPAD + c4 * 4] = pk;
}

// ---------- BN0 stats -> affine coeffs (+ bias zero-init folded in) ----------
__global__ void k_bn0(const float* __restrict__ E, const int* __restrict__ e1,
                      const float* __restrict__ g, const float* __restrict__ b,
                      float* __restrict__ A, float* __restrict__ Bc,
                      float* __restrict__ bias) {
  int f = blockIdx.x, ln = threadIdx.x;
  float s1 = 0.f, s2 = 0.f;
  for (int i = ln; i < BSZ; i += 64) {
    float v = E[(long)e1[i] * DIM + f];
    s1 += v; s2 += v * v;
  }
  s1 = wredf(s1); s2 = wredf(s2);
  if (ln == 0) {
    float m = s1 / BSZ;
    float var = s2 / BSZ - m * m;
    float a = g[f] * rsqrtf(var + EPSV);
    A[f] = a; Bc[f] = b[f] - m * a;
    bias[f] = 0.f;
  }
}

// ---------- x1 = bn0(E[e1]) @ e_W  (512 x 2000), 16x128 tiles ----------
__global__ void __launch_bounds__(256) k_mm1(
    const float* __restrict__ E, const int* __restrict__ e1,
    const float* __restrict__ eW, const float* __restrict__ A,
    const float* __restrict__ Bc, float* __restrict__ x1) {
  __shared__ float xs[16][DIM];  // 12.8 KB
  int t = threadIdx.x;
  int b0 = blockIdx.x * 16, n0 = blockIdx.y * 128;
  for (int idx = t; idx < 16 * DIM; idx += 256) {
    int bi = idx / DIM, f = idx % DIM;
    xs[bi][f] = E[(long)e1[b0 + bi] * DIM + f] * A[f] + Bc[f];
  }
  __syncthreads();
  int lane = t & 63, w = t >> 6;
  int j0 = n0 + lane, j1 = j0 + 64;
  int r0 = w * 4;
  bool c0 = (j0 < ODIM), c1 = (j1 < ODIM);
  float acc[4][2];
#pragma unroll
  for (int r = 0; r < 4; r++) { acc[r][0] = 0.f; acc[r][1] = 0.f; }
  for (int k = 0; k < DIM; k += 4) {
    f32x4 xr[4];
#pragma unroll
    for (int r = 0; r < 4; r++) xr[r] = *(const f32x4*)&xs[r0 + r][k];
#pragma unroll
    for (int kk = 0; kk < 4; kk++) {
      float e0v = c0 ? eW[(long)(k + kk) * ODIM + j0] : 0.f;
      float e1v = c1 ? eW[(long)(k + kk) * ODIM + j1] : 0.f;
#pragma unroll
      for (int r = 0; r < 4; r++) {
        acc[r][0] += xr[r][kk] * e0v;
        acc[r][1] += xr[r][kk] * e1v;
      }
    }
  }
#pragma unroll
  for (int r = 0; r < 4; r++) {
    long base = (long)(b0 + r0 + r) * ODIM;
    if (c0) x1[base + j0] = acc[r][0];
    if (c1) x1[base + j1] = acc[r][1];
  }
}

// ---------- conv -> convF bf16 in MFMA-fragment order + BN1 partials ----------
// Fragment layout: addr16B(mt,kb,quad,lm) with row b = mt*16+lm, col8 = o*249+t,
// kb = col8>>2, quad = col8&3:  convF[ (mt*NKB*64 + col8*16 + lm) * 8 ].
// gemm_fc then loads one contiguous 1 KB fragment per wave instruction.
__global__ void __launch_bounds__(256) k_conv(
    const float* __restrict__ x1, const float* __restrict__ R,
    const int* __restrict__ ridx, unsigned short* __restrict__ convF,
    float* __restrict__ part) {
  __shared__ float xs[ODIM];
  __shared__ float kr[OCH * KERN];
  __shared__ float wr4[4][64];
  int t = threadIdx.x, b = blockIdx.x;
  for (int i = t; i < ODIM; i += 256) xs[i] = x1[(long)b * ODIM + i];
  for (int i = t; i < OCH * KERN; i += 256) kr[i] = R[(long)ridx[b] * (OCH * KERN) + i];
  __syncthreads();
  int l0 = t * 8;
  bool act = (t < 249);  // 249*8 = 1992 outputs per channel
  float w[16];
  if (act) {
#pragma unroll
    for (int i = 0; i < 16; i++) w[i] = xs[l0 + i];
  }
  int wv = t >> 6, ln = t & 63;
  long fbase = (long)(b >> 4) * (NKB * 64) + (b & 15);
  for (int o = 0; o < OCH; o++) {
    float s1 = 0.f, s2 = 0.f;
    if (act) {
      float kk[KERN];
#pragma unroll
      for (int k = 0; k < KERN; k++) kk[k] = kr[o * KERN + k];
      float cb[8];
#pragma unroll
      for (int j = 0; j < 8; j++) {
        float c = 0.f;
#pragma unroll
        for (int k = 0; k < KERN; k++) c += kk[k] * w[j + k];
        cb[j] = c; s1 += c; s2 += c * c;
      }
      uint4v pk;
#pragma unroll
      for (int i = 0; i < 4; i++)
        pk[i] = (unsigned)f2bf(cb[2 * i]) | ((unsigned)f2bf(cb[2 * i + 1]) << 16);
      *(uint4v*)(convF + (fbase + (long)(o * 249 + t) * 16) * 8) = pk;
    }
    s1 = wredf(s1); s2 = wredf(s2);
    if (ln == 0) { wr4[wv][o] = s1; wr4[wv][o + 32] = s2; }
  }
  __syncthreads();
  if (t < 64) part[(long)b * 64 + t] = wr4[0][t] + wr4[1][t] + wr4[2][t] + wr4[3][t];
}

// ---------- finalize BN1 -> a[o], c[o] ----------
__global__ void k_bn1fin(const float* __restrict__ part, const float* __restrict__ g,
                         const float* __restrict__ b, float* __restrict__ a,
                         float* __restrict__ c) {
  __shared__ float sm[4][64];
  __shared__ float tot[64];
  int t = threadIdx.x;
  int si = t >> 6, st = t & 63;
  float s = 0.f;
  for (int i = si; i < BSZ; i += 4) s += part[(long)i * 64 + st];
  sm[si][st] = s;
  __syncthreads();
  if (t < 64) tot[t] = sm[0][t] + sm[1][t] + sm[2][t] + sm[3][t];
  __syncthreads();
  if (t < OCH) {
    float N = (float)BSZ * LOUT;
    float m = tot[t] / N;
    float var = tot[t + 32] / N - m * m;
    float av = g[t] * rsqrtf(var + EPSV);
    a[t] = av; c[t] = b[t] - m * av;
  }
}

// ---------- fcW fp32 -> fcF bf16 (fragment order, scaled by a[o]) ----------
// Same fragment formula with row = d. fcF has 256 padded rows (mt 0..15);
// rows 200..255 stay uninitialized -> garbage only in unread ypart columns.
__global__ void __launch_bounds__(256) k_fcw(
    const float* __restrict__ fcW, const float* __restrict__ a,
    const float* __restrict__ c, unsigned short* __restrict__ fcF,
    float* __restrict__ bias) {
  int d = blockIdx.x, o = blockIdx.y, t = threadIdx.x;
  const float* src = fcW + (long)d * FCLEN + o * LOUT;
  float ao = a[o];
  float s = 0.f;
  if (t < 249) {
    float v[8];
#pragma unroll
    for (int j = 0; j < 8; j++) { v[j] = src[t * 8 + j]; s += v[j]; }
    uint4v pk;
#pragma unroll
    for (int i = 0; i < 4; i++)
      pk[i] = (unsigned)f2bf(v[2 * i] * ao) | ((unsigned)f2bf(v[2 * i + 1] * ao) << 16);
    long fb = (long)(d >> 4) * (NKB * 64) + (long)(o * 249 + t) * 16 + (d & 15);
    *(uint4v*)(fcF + fb * 8) = pk;
  }
  s = wredf(s);
  __shared__ float sm[4];
  if ((t & 63) == 0) sm[t >> 6] = s;
  __syncthreads();
  if (t == 0) atomicAdd(bias + d, c[o] * (sm[0] + sm[1] + sm[2] + sm[3]));
}

// ---------- fc GEMM: no LDS, no barriers; fragment-direct streaming ----------
// ypart[z] = convF(128-row tile) @ fcF^T(128-row tile) over this z's kb range.
// Every A/B fragment load = one contiguous 1 KB global_load_dwordx4 per wave.
__global__ void __launch_bounds__(256) k_gemm_fc(
    const unsigned short* __restrict__ convF, const unsigned short* __restrict__ fcF,
    float* __restrict__ ypart) {
  int t = threadIdx.x;
  int b0 = blockIdx.x * 128, n0 = blockIdx.y * 128, z = blockIdx.z;
  int s0 = (NKB * z) / NZ, s1 = (NKB * (z + 1)) / NZ;
  int w = t >> 6, lane = t & 63, lm = lane & 15, quad = lane >> 4;
  int mq = (w >> 1) * 64, nq = (w & 1) * 64;
  int mt0 = (b0 + mq) >> 4, nt0 = (n0 + nq) >> 4;
  f32x4 acc[4][4];
#pragma unroll
  for (int mi = 0; mi < 4; mi++)
#pragma unroll
    for (int ni = 0; ni < 4; ni++) acc[mi][ni] = (f32x4){0.f, 0.f, 0.f, 0.f};
#pragma unroll 2
  for (int kb = s0; kb < s1; kb++) {
    short8 af[4], bfr[4];
#pragma unroll
    for (int i = 0; i < 4; i++) {
      af[i] = *(const short8*)&convF[((((long)(mt0 + i) * NKB + kb) * 4 + quad) * 16 + lm) * 8];
      bfr[i] = *(const short8*)&fcF[((((long)(nt0 + i) * NKB + kb) * 4 + quad) * 16 + lm) * 8];
    }
#pragma unroll
    for (int mi = 0; mi < 4; mi++)
#pragma unroll
      for (int ni = 0; ni < 4; ni++)
        acc[mi][ni] = __builtin_amdgcn_mfma_f32_16x16x32_bf16(
            __builtin_bit_cast(bf16x8, af[mi]), __builtin_bit_cast(bf16x8, bfr[ni]),
            acc[mi][ni], 0, 0, 0);
  }
#pragma unroll
  for (int mi = 0; mi < 4; mi++)
#pragma unroll
    for (int ni = 0; ni < 4; ni++)
#pragma unroll
      for (int r = 0; r < 4; r++) {
        int gm = b0 + mq + mi * 16 + quad * 4 + r;
        int gn = n0 + nq + ni * 16 + lm;
        ypart[((long)z * BSZ + gm) * 256 + gn] = acc[mi][ni][r];
      }
}

// ---------- reduce split-K partials + bias -> y[512][200] ----------
__global__ void __launch_bounds__(256) k_yred(
    const float* __restrict__ ypart, const float* __restrict__ bias,
    float* __restrict__ y) {
  int i = blockIdx.x * 256 + threadIdx.x;  // 102400 total
  int m = i / DIM, d = i % DIM;
  float s = bias[d];
#pragma unroll 8
  for (int z = 0; z < NZ; z++) s += ypart[((long)z * BSZ + m) * 256 + d];
  y[(long)m * DIM + d] = s;
}

// ---------- BN2 + tanh -> xtf bf16 in MFMA-fragment order ----------
__global__ void k_bn2(const float* __restrict__ y, const float* __restrict__ g,
                      const float* __restrict__ b, unsigned short* __restrict__ xtf) {
  int d = blockIdx.x, ln = threadIdx.x;
  int ks = d >> 5, quad = (d >> 3) & 3, e = d & 7;
  if (d >= DIM) {
    for (int j = 0; j < 8; j++) {
      int row = ln + 64 * j;
      xtf[((((long)(row >> 4) * 7 + ks) * 64) + quad * 16 + (row & 15)) * 8 + e] = 0;
    }
    return;
  }
  float v[8];
  float s1 = 0.f, s2 = 0.f;
#pragma unroll
  for (int j = 0; j < 8; j++) {
    v[j] = y[(long)(ln + 64 * j) * DIM + d];
    s1 += v[j]; s2 += v[j] * v[j];
  }
  s1 = wredf(s1); s2 = wredf(s2);
  s1 = __shfl(s1, 0, 64); s2 = __shfl(s2, 0, 64);
  float m = s1 / BSZ, var = s2 / BSZ - m * m;
  float a = g[d] * rsqrtf(var + EPSV), c = b[d] - m * a;
#pragma unroll
  for (int j = 0; j < 8; j++) {
    int row = ln + 64 * j;
    xtf[((((long)(row >> 4) * 7 + ks) * 64) + quad * 16 + (row & 15)) * 8 + e] =
        f2bf(tanhf(v[j] * a + c));
  }
}

// ---------- final GEMM: out = sigmoid(xt @ Ebf^T) ----------
// 1-D grid 3128, XCD swizzle: my = id & 7 -> each XCD owns one 64-row
// m-group, streams the full Ebf sequentially (L2-friendly), and its writes
// concentrate in 64 output rows (DRAM page locality). Only change vs r3.
__global__ void __launch_bounds__(256, 4) k_gemmf(
    const unsigned short* __restrict__ xtf, const unsigned short* __restrict__ Ebf,
    float* __restrict__ out) {
  __shared__ float lds[32][260];  // 33.28 KB
  int t = threadIdx.x;
  int id = blockIdx.x;
  int my = id & 7, bx = id >> 3;
  int w = t >> 6, lane = t & 63, lm = lane & 15, quad = lane >> 4;
  long ew = (long)bx * 256 + w * 64;  // this wave's 64-entity stripe
  int m0 = my * 64;                   // this block's 64 batch rows
  int mtb = my * 4;                   // A fragment-tile base (16-row tiles)
  f32x4 acc[4][4];
#pragma unroll
  for (int mi = 0; mi < 4; mi++)
#pragma unroll
    for (int ni = 0; ni < 4; ni++) acc[mi][ni] = (f32x4){0.f, 0.f, 0.f, 0.f};
  for (int kk = 0; kk < 7; kk++) {
    int k0 = kk * 32;
    short8 bfr[4], af[4];
#pragma unroll
    for (int ni = 0; ni < 4; ni++)
      bfr[ni] = *(const short8*)&Ebf[(ew + ni * 16 + lm) * KPAD + k0 + quad * 8];
#pragma unroll
    for (int mi = 0; mi < 4; mi++)
      af[mi] = *(const short8*)&xtf[(((long)(mtb + mi) * 7 + kk) * 64 + lane) * 8];
#pragma unroll
    for (int mi = 0; mi < 4; mi++)
#pragma unroll
      for (int ni = 0; ni < 4; ni++)
        acc[mi][ni] = __builtin_amdgcn_mfma_f32_16x16x32_bf16(
            __builtin_bit_cast(bf16x8, af[mi]), __builtin_bit_cast(bf16x8, bfr[ni]),
            acc[mi][ni], 0, 0, 0);
  }
  // epilogue: two 32-row halves through LDS -> 1 KB contiguous stores
  long ge = (long)bx * 256 + lane * 4;
#pragma unroll
  for (int h = 0; h < 2; h++) {
    if (h) __syncthreads();
#pragma unroll
    for (int mh = 0; mh < 2; mh++) {
      int mi = 2 * h + mh;
#pragma unroll
      for (int ni = 0; ni < 4; ni++)
#pragma unroll
        for (int r = 0; r < 4; r++)
          lds[mh * 16 + quad * 4 + r][w * 64 + ni * 16 + lm] = acc[mi][ni][r];
    }
    __syncthreads();
    if (ge < NENT) {
#pragma unroll
      for (int i = 0; i < 8; i++) {
        int R = w * 8 + i;
        f32x4 v = *(const f32x4*)&lds[R][lane * 4];
        f32x4 sg;
#pragma unroll
        for (int j = 0; j < 4; j++) sg[j] = 1.f / (1.f + __expf(-v[j]));
        *(f32x4*)&out[(long)(m0 + 32 * h + R) * NENT + ge] = sg;
      }
    }
  }
}

extern "C" void kernel_launch(void* const* d_in, const int* in_sizes, int n_in,
                              void* d_out, int out_size, void* d_ws, size_t ws_size,
                              hipStream_t stream) {
  const float* E = (const float*)d_in[0];
  const float* R = (const float*)d_in[1];
  const float* eW = (const float*)d_in[2];
  const float* fcW = (const float*)d_in[3];
  const float* bn0g = (const float*)d_in[4];
  const float* bn0b = (const float*)d_in[5];
  const float* bn1g = (const float*)d_in[6];
  const float* bn1b = (const float*)d_in[7];
  const float* bn2g = (const float*)d_in[8];
  const float* bn2b = (const float*)d_in[9];
  const int* e1 = (const int*)d_in[10];
  const int* ridx = (const int*)d_in[11];
  float* outp = (float*)d_out;

  char* p = (char*)d_ws;
  size_t off = 0;
  auto alloc = [&](size_t bytes) -> char* {
    char* r = p + off;
    off = (off + bytes + 255) & ~(size_t)255;
    return r;
  };
  float* x1 = (float*)alloc((size_t)BSZ * ODIM * 4);
  unsigned short* convF = (unsigned short*)alloc((size_t)32 * NKB * 512 * 2);
  unsigned short* fcF = (unsigned short*)alloc((size_t)16 * NKB * 512 * 2);
  unsigned short* Ebf = (unsigned short*)alloc((size_t)EROWS * KPAD * 2);
  float* ypart = (float*)alloc((size_t)NZ * BSZ * 256 * 4);
  float* y = (float*)alloc((size_t)BSZ * DIM * 4);
  unsigned short* xtf = (unsigned short*)alloc((size_t)BSZ * KPAD * 2);
  float* bn0A = (float*)alloc(DIM * 4);
  float* bn0B = (float*)alloc(DIM * 4);
  float* part = (float*)alloc((size_t)BSZ * 64 * 4);
  float* bn1a = (float*)alloc(OCH * 4);
  float* bn1c = (float*)alloc(OCH * 4);
  float* bias = (float*)alloc(DIM * 4);

  k_probe<<<800, 256, 0, stream>>>(outp);  // d_out write-BW diagnostic
  k_ebf<<<(EROWS * 56) / 256, 256, 0, stream>>>(E, Ebf);
  k_bn0<<<DIM, 64, 0, stream>>>(E, e1, bn0g, bn0b, bn0A, bn0B, bias);
  k_mm1<<<dim3(32, 16), 256, 0, stream>>>(E, e1, eW, bn0A, bn0B, x1);
  k_conv<<<BSZ, 256, 0, stream>>>(x1, R, ridx, convF, part);
  k_bn1fin<<<1, 256, 0, stream>>>(part, bn1g, bn1b, bn1a, bn1c);
  k_fcw<<<dim3(DIM, OCH), 256, 0, stream>>>(fcW, bn1a, bn1c, fcF, bias);
  k_gemm_fc<<<dim3(4, 2, NZ), 256, 0, stream>>>(convF, fcF, ypart);
  k_yred<<<400, 256, 0, stream>>>(ypart, bias, y);
  k_bn2<<<KPAD, 64, 0, stream>>>(y, bn2g, bn2b, xtf);
  k_gemmf<<<3128, 256, 0, stream>>>(xtf, Ebf, outp);
}

// Round 5
// 609.595 us; speedup vs baseline: 1.0768x; 1.0768x over previous
//
#include <hip/hip_runtime.h>

#define NENT 100000
#define DIM 200
#define ODIM 2000
#define KERN 9
#define OCH 32
#define LOUT 1992
#define FCLEN 63744
#define BSZ 512
#define EPSV 1e-5f
#define KPAD 224
#define NZ 64
#define EROWS 100096  // 391 * 256, Ebf rows padded (zeros past NENT)

typedef float f32x4 __attribute__((ext_vector_type(4)));
typedef short short8 __attribute__((ext_vector_type(8)));
typedef __bf16 bf16x8 __attribute__((ext_vector_type(8)));
typedef unsigned int uint4v __attribute__((ext_vector_type(4)));
typedef unsigned int uint2v __attribute__((ext_vector_type(2)));

__device__ __forceinline__ unsigned short f2bf(float f) {
  unsigned int u = __float_as_uint(f);
  return (unsigned short)((u + 0x7fffu + ((u >> 16) & 1u)) >> 16);
}

__device__ __forceinline__ float wredf(float v) {
#pragma unroll
  for (int o = 32; o > 0; o >>= 1) v += __shfl_down(v, o, 64);
  return v;
}

// ---------- DIAGNOSTIC v2: write d_out TWICE, contiguous fill-pattern ----------
// 410 MB total. Decision threshold now straddles the top-5 cut (~123 us):
// normal memory -> ~62 us (ABSENT from top-5); slow-path d_out -> ~230 us
// (TOPS the chart). Overwritten by k_gemmf afterwards, so correctness is
// unaffected.
__global__ void __launch_bounds__(256) k_probe(float* __restrict__ out) {
  const f32x4 v = (f32x4){0.5f, 0.5f, 0.5f, 0.5f};
  long base = (long)(blockIdx.x % 800) * 16384 + threadIdx.x;
#pragma unroll
  for (int i = 0; i < 64; i++) {
    long idx = base + (long)i * 256;
    if (idx < 12800000L) *(f32x4*)&out[idx * 4] = v;
  }
}

// ---------- E fp32 -> Ebf bf16 [EROWS][KPAD], zero-padded K and rows ----------
__global__ void __launch_bounds__(256) k_ebf(const float* __restrict__ E,
                                             unsigned short* __restrict__ Ebf) {
  long idx = (long)blockIdx.x * 256 + threadIdx.x;  // EROWS*56 total
  int row = (int)(idx / 56), c4 = (int)(idx % 56);
  f32x4 v = (f32x4){0.f, 0.f, 0.f, 0.f};
  if (row < NENT && c4 < 50) v = *(const f32x4*)&E[(long)row * DIM + c4 * 4];
  uint2v pk;
  pk[0] = (unsigned)f2bf(v[0]) | ((unsigned)f2bf(v[1]) << 16);
  pk[1] = (unsigned)f2bf(v[2]) | ((unsigned)f2bf(v[3]) << 16);
  *(uint2v*)&Ebf[(long)row * KPAD + c4 * 4] = pk;
}

// ---------- BN0 stats -> affine coeffs (+ bias zero-init folded in) ----------
__global__ void k_bn0(const float* __restrict__ E, const int* __restrict__ e1,
                      const float* __restrict__ g, const float* __restrict__ b,
                      float* __restrict__ A, float* __restrict__ Bc,
                      float* __restrict__ bias) {
  int f = blockIdx.x, ln = threadIdx.x;
  float s1 = 0.f, s2 = 0.f;
  for (int i = ln; i < BSZ; i += 64) {
    float v = E[(long)e1[i] * DIM + f];
    s1 += v; s2 += v * v;
  }
  s1 = wredf(s1); s2 = wredf(s2);
  if (ln == 0) {
    float m = s1 / BSZ;
    float var = s2 / BSZ - m * m;
    float a = g[f] * rsqrtf(var + EPSV);
    A[f] = a; Bc[f] = b[f] - m * a;
    bias[f] = 0.f;
  }
}

// ---------- x1 = bn0(E[e1]) @ e_W  (512 x 2000), 16x128 tiles ----------
__global__ void __launch_bounds__(256) k_mm1(
    const float* __restrict__ E, const int* __restrict__ e1,
    const float* __restrict__ eW, const float* __restrict__ A,
    const float* __restrict__ Bc, float* __restrict__ x1) {
  __shared__ float xs[16][DIM];  // 12.8 KB
  int t = threadIdx.x;
  int b0 = blockIdx.x * 16, n0 = blockIdx.y * 128;
  for (int idx = t; idx < 16 * DIM; idx += 256) {
    int bi = idx / DIM, f = idx % DIM;
    xs[bi][f] = E[(long)e1[b0 + bi] * DIM + f] * A[f] + Bc[f];
  }
  __syncthreads();
  int lane = t & 63, w = t >> 6;
  int j0 = n0 + lane, j1 = j0 + 64;
  int r0 = w * 4;
  bool c0 = (j0 < ODIM), c1 = (j1 < ODIM);
  float acc[4][2];
#pragma unroll
  for (int r = 0; r < 4; r++) { acc[r][0] = 0.f; acc[r][1] = 0.f; }
  for (int k = 0; k < DIM; k += 4) {
    f32x4 xr[4];
#pragma unroll
    for (int r = 0; r < 4; r++) xr[r] = *(const f32x4*)&xs[r0 + r][k];
#pragma unroll
    for (int kk = 0; kk < 4; kk++) {
      float e0v = c0 ? eW[(long)(k + kk) * ODIM + j0] : 0.f;
      float e1v = c1 ? eW[(long)(k + kk) * ODIM + j1] : 0.f;
#pragma unroll
      for (int r = 0; r < 4; r++) {
        acc[r][0] += xr[r][kk] * e0v;
        acc[r][1] += xr[r][kk] * e1v;
      }
    }
  }
#pragma unroll
  for (int r = 0; r < 4; r++) {
    long base = (long)(b0 + r0 + r) * ODIM;
    if (c0) x1[base + j0] = acc[r][0];
    if (c1) x1[base + j1] = acc[r][1];
  }
}

// ---------- conv (per-sample filters) -> bf16 + per-block BN1 partial stats ----------
// (reverted to linear convb layout: fragment-order emit scattered 16 B
// writes across XCD-incoherent L2s -> partial-line writebacks, r4 regression)
__global__ void __launch_bounds__(256) k_conv(
    const float* __restrict__ x1, const float* __restrict__ R,
    const int* __restrict__ ridx, unsigned short* __restrict__ convb,
    float* __restrict__ part) {
  __shared__ float xs[ODIM];
  __shared__ float kr[OCH * KERN];
  __shared__ float wr4[4][64];
  int t = threadIdx.x, b = blockIdx.x;
  for (int i = t; i < ODIM; i += 256) xs[i] = x1[(long)b * ODIM + i];
  for (int i = t; i < OCH * KERN; i += 256) kr[i] = R[(long)ridx[b] * (OCH * KERN) + i];
  __syncthreads();
  int l0 = t * 8;
  bool act = (t < 249);  // 249*8 = 1992 outputs per channel
  float w[16];
  if (act) {
#pragma unroll
    for (int i = 0; i < 16; i++) w[i] = xs[l0 + i];
  }
  int wv = t >> 6, ln = t & 63;
  for (int o = 0; o < OCH; o++) {
    float s1 = 0.f, s2 = 0.f;
    if (act) {
      float kk[KERN];
#pragma unroll
      for (int k = 0; k < KERN; k++) kk[k] = kr[o * KERN + k];
      float cb[8];
#pragma unroll
      for (int j = 0; j < 8; j++) {
        float c = 0.f;
#pragma unroll
        for (int k = 0; k < KERN; k++) c += kk[k] * w[j + k];
        cb[j] = c; s1 += c; s2 += c * c;
      }
      uint4v pk;
#pragma unroll
      for (int i = 0; i < 4; i++)
        pk[i] = (unsigned)f2bf(cb[2 * i]) | ((unsigned)f2bf(cb[2 * i + 1]) << 16);
      *(uint4v*)(convb + (long)b * FCLEN + o * LOUT + l0) = pk;
    }
    s1 = wredf(s1); s2 = wredf(s2);
    if (ln == 0) { wr4[wv][o] = s1; wr4[wv][o + 32] = s2; }
  }
  __syncthreads();
  if (t < 64) part[(long)b * 64 + t] = wr4[0][t] + wr4[1][t] + wr4[2][t] + wr4[3][t];
}

// ---------- finalize BN1 -> a[o], c[o] ----------
__global__ void k_bn1fin(const float* __restrict__ part, const float* __restrict__ g,
                         const float* __restrict__ b, float* __restrict__ a,
                         float* __restrict__ c) {
  __shared__ float sm[4][64];
  __shared__ float tot[64];
  int t = threadIdx.x;
  int si = t >> 6, st = t & 63;
  float s = 0.f;
  for (int i = si; i < BSZ; i += 4) s += part[(long)i * 64 + st];
  sm[si][st] = s;
  __syncthreads();
  if (t < 64) tot[t] = sm[0][t] + sm[1][t] + sm[2][t] + sm[3][t];
  __syncthreads();
  if (t < OCH) {
    float N = (float)BSZ * LOUT;
    float m = tot[t] / N;
    float var = tot[t + 32] / N - m * m;
    float av = g[t] * rsqrtf(var + EPSV);
    a[t] = av; c[t] = b[t] - m * av;
  }
}

// ---------- fcW fp32 -> bf16 scaled by a[o]; bias[d] += c[o]*rowsum ----------
__global__ void __launch_bounds__(256) k_fcw(
    const float* __restrict__ fcW, const float* __restrict__ a,
    const float* __restrict__ c, unsigned short* __restrict__ fcWb,
    float* __restrict__ bias) {
  int d = blockIdx.x, o = blockIdx.y, t = threadIdx.x;
  const float* src = fcW + (long)d * FCLEN + o * LOUT;
  unsigned short* dst = fcWb + (long)d * FCLEN + o * LOUT;
  float ao = a[o];
  float s = 0.f;
  if (t < 249) {
    float v[8];
#pragma unroll
    for (int j = 0; j < 8; j++) { v[j] = src[t * 8 + j]; s += v[j]; }
    uint4v pk;
#pragma unroll
    for (int i = 0; i < 4; i++)
      pk[i] = (unsigned)f2bf(v[2 * i] * ao) | ((unsigned)f2bf(v[2 * i + 1] * ao) << 16);
    *(uint4v*)(dst + t * 8) = pk;
  }
  s = wredf(s);
  __shared__ float sm[4];
  if ((t & 63) == 0) sm[t >> 6] = s;
  __syncthreads();
  if (t == 0) atomicAdd(bias + d, c[o] * (sm[0] + sm[1] + sm[2] + sm[3]));
}

// ---------- fc GEMM: ypart[z] = conv(bf16) @ fcWb^T slice, 128x128 tile, BK=96 ----------
// (reverted to r3 LDS form, NZ=64: 512 blocks = 2 blocks/CU overlap)
__global__ void __launch_bounds__(256) k_gemm_fc(
    const unsigned short* __restrict__ convb, const unsigned short* __restrict__ fcWb,
    float* __restrict__ ypart) {
  __shared__ unsigned short lA[128 * 104];
  __shared__ unsigned short lB[128 * 104];
  int t = threadIdx.x;
  int b0 = blockIdx.x * 128, n0 = blockIdx.y * 128, z = blockIdx.z;
  int s0 = (664 * z) / NZ, s1 = (664 * (z + 1)) / NZ;  // 664 = 63744/96 steps
  int w = t >> 6, lane = t & 63, lm = lane & 15, quad = lane >> 4;
  int mq = (w >> 1) * 64, nq = (w & 1) * 64;
  f32x4 acc[4][4];
#pragma unroll
  for (int mi = 0; mi < 4; mi++)
#pragma unroll
    for (int ni = 0; ni < 4; ni++) acc[mi][ni] = (f32x4){0.f, 0.f, 0.f, 0.f};
  for (int st = s0; st < s1; st++) {
    long kc = (long)st * 96;
    __syncthreads();
#pragma unroll
    for (int i = 0; i < 6; i++) {  // 128 rows * 12 chunks = 1536 = 6*256
      int cc = t + 256 * i;
      int row = cc / 12, c8 = cc % 12;
      *(uint4v*)&lA[row * 104 + c8 * 8] =
          *(const uint4v*)&convb[(long)(b0 + row) * FCLEN + kc + c8 * 8];
      uint4v bv = (uint4v){0u, 0u, 0u, 0u};
      int nr = n0 + row;
      if (nr < DIM) bv = *(const uint4v*)&fcWb[(long)nr * FCLEN + kc + c8 * 8];
      *(uint4v*)&lB[row * 104 + c8 * 8] = bv;
    }
    __syncthreads();
#pragma unroll
    for (int ks = 0; ks < 96; ks += 32) {
      short8 af[4], bfr[4];
#pragma unroll
      for (int i2 = 0; i2 < 4; i2++) {
        af[i2] = *(const short8*)&lA[(mq + i2 * 16 + lm) * 104 + ks + quad * 8];
        bfr[i2] = *(const short8*)&lB[(nq + i2 * 16 + lm) * 104 + ks + quad * 8];
      }
#pragma unroll
      for (int mi = 0; mi < 4; mi++)
#pragma unroll
        for (int ni = 0; ni < 4; ni++)
          acc[mi][ni] = __builtin_amdgcn_mfma_f32_16x16x32_bf16(
              __builtin_bit_cast(bf16x8, af[mi]), __builtin_bit_cast(bf16x8, bfr[ni]),
              acc[mi][ni], 0, 0, 0);
    }
  }
  // write split-K partials (N padded to 256); no atomics
#pragma unroll
  for (int mi = 0; mi < 4; mi++)
#pragma unroll
    for (int ni = 0; ni < 4; ni++)
#pragma unroll
      for (int r = 0; r < 4; r++) {
        int gm = b0 + mq + mi * 16 + quad * 4 + r;
        int gn = n0 + nq + ni * 16 + lm;
        ypart[((long)z * BSZ + gm) * 256 + gn] = acc[mi][ni][r];
      }
}

// ---------- reduce split-K partials + bias -> y[512][200] ----------
__global__ void __launch_bounds__(256) k_yred(
    const float* __restrict__ ypart, const float* __restrict__ bias,
    float* __restrict__ y) {
  int i = blockIdx.x * 256 + threadIdx.x;  // 102400 total
  int m = i / DIM, d = i % DIM;
  float s = bias[d];
#pragma unroll 8
  for (int z = 0; z < NZ; z++) s += ypart[((long)z * BSZ + m) * 256 + d];
  y[(long)m * DIM + d] = s;
}

// ---------- BN2 + tanh -> xtf bf16 in MFMA-fragment order ----------
__global__ void k_bn2(const float* __restrict__ y, const float* __restrict__ g,
                      const float* __restrict__ b, unsigned short* __restrict__ xtf) {
  int d = blockIdx.x, ln = threadIdx.x;
  int ks = d >> 5, quad = (d >> 3) & 3, e = d & 7;
  if (d >= DIM) {
    for (int j = 0; j < 8; j++) {
      int row = ln + 64 * j;
      xtf[((((long)(row >> 4) * 7 + ks) * 64) + quad * 16 + (row & 15)) * 8 + e] = 0;
    }
    return;
  }
  float v[8];
  float s1 = 0.f, s2 = 0.f;
#pragma unroll
  for (int j = 0; j < 8; j++) {
    v[j] = y[(long)(ln + 64 * j) * DIM + d];
    s1 += v[j]; s2 += v[j] * v[j];
  }
  s1 = wredf(s1); s2 = wredf(s2);
  s1 = __shfl(s1, 0, 64); s2 = __shfl(s2, 0, 64);
  float m = s1 / BSZ, var = s2 / BSZ - m * m;
  float a = g[d] * rsqrtf(var + EPSV), c = b[d] - m * a;
#pragma unroll
  for (int j = 0; j < 8; j++) {
    int row = ln + 64 * j;
    xtf[((((long)(row >> 4) * 7 + ks) * 64) + quad * 16 + (row & 15)) * 8 + e] =
        f2bf(tanhf(v[j] * a + c));
  }
}

// ---------- final GEMM: out = sigmoid(xt @ Ebf^T) ----------
// 512-thread blocks (8 waves), grid 1563 1-D. Block = full M=512 x N=64:
// Ebf is read ONCE from DRAM chip-wide (all 8 waves load the identical
// B fragments -> 1 L2 miss + 7 L1 hits). No LDS, no barriers. A (xtf)
// contiguous fragments. Stores direct from acc: each inst = 4 full,
// aligned 64 B lines (r0 measured zero write amplification for this).
// VGPR <= 128 via launch_bounds -> 2 blocks/CU.
__global__ void __launch_bounds__(512, 4) k_gemmf(
    const unsigned short* __restrict__ xtf, const unsigned short* __restrict__ Ebf,
    float* __restrict__ out) {
  int t = threadIdx.x;
  int w = t >> 6, lane = t & 63, lm = lane & 15, quad = lane >> 4;
  long e0 = (long)blockIdx.x * 64;  // this block's 64-entity stripe
  int m0 = w * 64;                  // this wave's 64 batch rows
  int mtb = w * 4;                  // A fragment-tile base (16-row tiles)
  f32x4 acc[4][4];
#pragma unroll
  for (int mi = 0; mi < 4; mi++)
#pragma unroll
    for (int ni = 0; ni < 4; ni++) acc[mi][ni] = (f32x4){0.f, 0.f, 0.f, 0.f};
#pragma unroll
  for (int kk = 0; kk < 7; kk++) {
    short8 bfr[4], af[4];
#pragma unroll
    for (int ni = 0; ni < 4; ni++)
      bfr[ni] = *(const short8*)&Ebf[(e0 + ni * 16 + lm) * KPAD + kk * 32 + quad * 8];
#pragma unroll
    for (int mi = 0; mi < 4; mi++)
      af[mi] = *(const short8*)&xtf[(((long)(mtb + mi) * 7 + kk) * 64 + lane) * 8];
#pragma unroll
    for (int mi = 0; mi < 4; mi++)
#pragma unroll
      for (int ni = 0; ni < 4; ni++)
        acc[mi][ni] = __builtin_amdgcn_mfma_f32_16x16x32_bf16(
            __builtin_bit_cast(bf16x8, af[mi]), __builtin_bit_cast(bf16x8, bfr[ni]),
            acc[mi][ni], 0, 0, 0);
  }
#pragma unroll
  for (int mi = 0; mi < 4; mi++)
#pragma unroll
    for (int ni = 0; ni < 4; ni++) {
      long ge = e0 + ni * 16 + lm;
      bool ok = (ge < NENT);
#pragma unroll
      for (int r = 0; r < 4; r++) {
        int gm = m0 + mi * 16 + quad * 4 + r;
        if (ok) {
          float x = acc[mi][ni][r];
          out[(long)gm * NENT + ge] = 1.f / (1.f + __expf(-x));
        }
      }
    }
}

extern "C" void kernel_launch(void* const* d_in, const int* in_sizes, int n_in,
                              void* d_out, int out_size, void* d_ws, size_t ws_size,
                              hipStream_t stream) {
  const float* E = (const float*)d_in[0];
  const float* R = (const float*)d_in[1];
  const float* eW = (const float*)d_in[2];
  const float* fcW = (const float*)d_in[3];
  const float* bn0g = (const float*)d_in[4];
  const float* bn0b = (const float*)d_in[5];
  const float* bn1g = (const float*)d_in[6];
  const float* bn1b = (const float*)d_in[7];
  const float* bn2g = (const float*)d_in[8];
  const float* bn2b = (const float*)d_in[9];
  const int* e1 = (const int*)d_in[10];
  const int* ridx = (const int*)d_in[11];
  float* outp = (float*)d_out;

  char* p = (char*)d_ws;
  size_t off = 0;
  auto alloc = [&](size_t bytes) -> char* {
    char* r = p + off;
    off = (off + bytes + 255) & ~(size_t)255;
    return r;
  };
  float* x1 = (float*)alloc((size_t)BSZ * ODIM * 4);
  unsigned short* convb = (unsigned short*)alloc((size_t)BSZ * FCLEN * 2);
  unsigned short* fcWb = (unsigned short*)alloc((size_t)DIM * FCLEN * 2);
  unsigned short* Ebf = (unsigned short*)alloc((size_t)EROWS * KPAD * 2);
  float* ypart = (float*)alloc((size_t)NZ * BSZ * 256 * 4);
  float* y = (float*)alloc((size_t)BSZ * DIM * 4);
  unsigned short* xtf = (unsigned short*)alloc((size_t)BSZ * KPAD * 2);
  float* bn0A = (float*)alloc(DIM * 4);
  float* bn0B = (float*)alloc(DIM * 4);
  float* part = (float*)alloc((size_t)BSZ * 64 * 4);
  float* bn1a = (float*)alloc(OCH * 4);
  float* bn1c = (float*)alloc(OCH * 4);
  float* bias = (float*)alloc(DIM * 4);

  k_probe<<<1600, 256, 0, stream>>>(outp);  // decisive d_out write-BW probe (2x 205 MB)
  k_ebf<<<(EROWS * 56) / 256, 256, 0, stream>>>(E, Ebf);
  k_bn0<<<DIM, 64, 0, stream>>>(E, e1, bn0g, bn0b, bn0A, bn0B, bias);
  k_mm1<<<dim3(32, 16), 256, 0, stream>>>(E, e1, eW, bn0A, bn0B, x1);
  k_conv<<<BSZ, 256, 0, stream>>>(x1, R, ridx, convb, part);
  k_bn1fin<<<1, 256, 0, stream>>>(part, bn1g, bn1b, bn1a, bn1c);
  k_fcw<<<dim3(DIM, OCH), 256, 0, stream>>>(fcW, bn1a, bn1c, fcWb, bias);
  k_gemm_fc<<<dim3(4, 2, NZ), 256, 0, stream>>>(convb, fcWb, ypart);
  k_yred<<<400, 256, 0, stream>>>(ypart, bias, y);
  k_bn2<<<KPAD, 64, 0, stream>>>(y, bn2g, bn2b, xtf);
  k_gemmf<<<1563, 512, 0, stream>>>(xtf, Ebf, outp);
}

// Round 7
// 572.724 us; speedup vs baseline: 1.1461x; 1.0644x over previous
//
#include <hip/hip_runtime.h>

#define NENT 100000
#define DIM 200
#define ODIM 2000
#define KERN 9
#define OCH 32
#define LOUT 1992
#define FCLEN 63744
#define BSZ 512
#define EPSV 1e-5f
#define KPAD 224
#define NZ 64

typedef float f32x4 __attribute__((ext_vector_type(4)));
typedef short short8 __attribute__((ext_vector_type(8)));
typedef __bf16 bf16x8 __attribute__((ext_vector_type(8)));
typedef unsigned int uint4v __attribute__((ext_vector_type(4)));
typedef unsigned int uint2v __attribute__((ext_vector_type(2)));

__device__ __forceinline__ unsigned short f2bf(float f) {
  unsigned int u = __float_as_uint(f);
  return (unsigned short)((u + 0x7fffu + ((u >> 16) & 1u)) >> 16);
}

__device__ __forceinline__ float wredf(float v) {
#pragma unroll
  for (int o = 32; o > 0; o >>= 1) v += __shfl_down(v, o, 64);
  return v;
}

// ---------- BN0 stats -> affine coeffs (+ bias zero-init folded in) ----------
__global__ void k_bn0(const float* __restrict__ E, const int* __restrict__ e1,
                      const float* __restrict__ g, const float* __restrict__ b,
                      float* __restrict__ A, float* __restrict__ Bc,
                      float* __restrict__ bias) {
  int f = blockIdx.x, ln = threadIdx.x;
  float s1 = 0.f, s2 = 0.f;
  for (int i = ln; i < BSZ; i += 64) {
    float v = E[(long)e1[i] * DIM + f];
    s1 += v; s2 += v * v;
  }
  s1 = wredf(s1); s2 = wredf(s2);
  if (ln == 0) {
    float m = s1 / BSZ;
    float var = s2 / BSZ - m * m;
    float a = g[f] * rsqrtf(var + EPSV);
    A[f] = a; Bc[f] = b[f] - m * a;
    bias[f] = 0.f;
  }
}

// ---------- x1 = bn0(E[e1]) @ e_W  (512 x 2000), 16x128 tiles ----------
__global__ void __launch_bounds__(256) k_mm1(
    const float* __restrict__ E, const int* __restrict__ e1,
    const float* __restrict__ eW, const float* __restrict__ A,
    const float* __restrict__ Bc, float* __restrict__ x1) {
  __shared__ float xs[16][DIM];  // 12.8 KB
  int t = threadIdx.x;
  int b0 = blockIdx.x * 16, n0 = blockIdx.y * 128;
  for (int idx = t; idx < 16 * DIM; idx += 256) {
    int bi = idx / DIM, f = idx % DIM;
    xs[bi][f] = E[(long)e1[b0 + bi] * DIM + f] * A[f] + Bc[f];
  }
  __syncthreads();
  int lane = t & 63, w = t >> 6;
  int j0 = n0 + lane, j1 = j0 + 64;
  int r0 = w * 4;
  bool c0 = (j0 < ODIM), c1 = (j1 < ODIM);
  float acc[4][2];
#pragma unroll
  for (int r = 0; r < 4; r++) { acc[r][0] = 0.f; acc[r][1] = 0.f; }
  for (int k = 0; k < DIM; k += 4) {
    f32x4 xr[4];
#pragma unroll
    for (int r = 0; r < 4; r++) xr[r] = *(const f32x4*)&xs[r0 + r][k];
#pragma unroll
    for (int kk = 0; kk < 4; kk++) {
      float e0v = c0 ? eW[(long)(k + kk) * ODIM + j0] : 0.f;
      float e1v = c1 ? eW[(long)(k + kk) * ODIM + j1] : 0.f;
#pragma unroll
      for (int r = 0; r < 4; r++) {
        acc[r][0] += xr[r][kk] * e0v;
        acc[r][1] += xr[r][kk] * e1v;
      }
    }
  }
#pragma unroll
  for (int r = 0; r < 4; r++) {
    long base = (long)(b0 + r0 + r) * ODIM;
    if (c0) x1[base + j0] = acc[r][0];
    if (c1) x1[base + j1] = acc[r][1];
  }
}

// ---------- conv (per-sample filters) -> bf16 + per-block BN1 partial stats ----------
__global__ void __launch_bounds__(256) k_conv(
    const float* __restrict__ x1, const float* __restrict__ R,
    const int* __restrict__ ridx, unsigned short* __restrict__ convb,
    float* __restrict__ part) {
  __shared__ float xs[ODIM];
  __shared__ float kr[OCH * KERN];
  __shared__ float wr4[4][64];
  int t = threadIdx.x, b = blockIdx.x;
  for (int i = t; i < ODIM; i += 256) xs[i] = x1[(long)b * ODIM + i];
  for (int i = t; i < OCH * KERN; i += 256) kr[i] = R[(long)ridx[b] * (OCH * KERN) + i];
  __syncthreads();
  int l0 = t * 8;
  bool act = (t < 249);  // 249*8 = 1992 outputs per channel
  float w[16];
  if (act) {
#pragma unroll
    for (int i = 0; i < 16; i++) w[i] = xs[l0 + i];
  }
  int wv = t >> 6, ln = t & 63;
  for (int o = 0; o < OCH; o++) {
    float s1 = 0.f, s2 = 0.f;
    if (act) {
      float kk[KERN];
#pragma unroll
      for (int k = 0; k < KERN; k++) kk[k] = kr[o * KERN + k];
      float cb[8];
#pragma unroll
      for (int j = 0; j < 8; j++) {
        float c = 0.f;
#pragma unroll
        for (int k = 0; k < KERN; k++) c += kk[k] * w[j + k];
        cb[j] = c; s1 += c; s2 += c * c;
      }
      uint4v pk;
#pragma unroll
      for (int i = 0; i < 4; i++)
        pk[i] = (unsigned)f2bf(cb[2 * i]) | ((unsigned)f2bf(cb[2 * i + 1]) << 16);
      *(uint4v*)(convb + (long)b * FCLEN + o * LOUT + l0) = pk;
    }
    s1 = wredf(s1); s2 = wredf(s2);
    if (ln == 0) { wr4[wv][o] = s1; wr4[wv][o + 32] = s2; }
  }
  __syncthreads();
  if (t < 64) part[(long)b * 64 + t] = wr4[0][t] + wr4[1][t] + wr4[2][t] + wr4[3][t];
}

// ---------- finalize BN1 -> a[o], c[o] ----------
__global__ void k_bn1fin(const float* __restrict__ part, const float* __restrict__ g,
                         const float* __restrict__ b, float* __restrict__ a,
                         float* __restrict__ c) {
  __shared__ float sm[4][64];
  __shared__ float tot[64];
  int t = threadIdx.x;
  int si = t >> 6, st = t & 63;
  float s = 0.f;
  for (int i = si; i < BSZ; i += 4) s += part[(long)i * 64 + st];
  sm[si][st] = s;
  __syncthreads();
  if (t < 64) tot[t] = sm[0][t] + sm[1][t] + sm[2][t] + sm[3][t];
  __syncthreads();
  if (t < OCH) {
    float N = (float)BSZ * LOUT;
    float m = tot[t] / N;
    float var = tot[t + 32] / N - m * m;
    float av = g[t] * rsqrtf(var + EPSV);
    a[t] = av; c[t] = b[t] - m * av;
  }
}

// ---------- fcW fp32 -> bf16 scaled by a[o]; bias[d] += c[o]*rowsum ----------
__global__ void __launch_bounds__(256) k_fcw(
    const float* __restrict__ fcW, const float* __restrict__ a,
    const float* __restrict__ c, unsigned short* __restrict__ fcWb,
    float* __restrict__ bias) {
  int d = blockIdx.x, o = blockIdx.y, t = threadIdx.x;
  const float* src = fcW + (long)d * FCLEN + o * LOUT;
  unsigned short* dst = fcWb + (long)d * FCLEN + o * LOUT;
  float ao = a[o];
  float s = 0.f;
  if (t < 249) {
    float v[8];
#pragma unroll
    for (int j = 0; j < 8; j++) { v[j] = src[t * 8 + j]; s += v[j]; }
    uint4v pk;
#pragma unroll
    for (int i = 0; i < 4; i++)
      pk[i] = (unsigned)f2bf(v[2 * i] * ao) | ((unsigned)f2bf(v[2 * i + 1] * ao) << 16);
    *(uint4v*)(dst + t * 8) = pk;
  }
  s = wredf(s);
  __shared__ float sm[4];
  if ((t & 63) == 0) sm[t >> 6] = s;
  __syncthreads();
  if (t == 0) atomicAdd(bias + d, c[o] * (sm[0] + sm[1] + sm[2] + sm[3]));
}

// ---------- fc GEMM: ypart[z] = conv(bf16) @ fcWb^T slice, 128x128 tile, BK=96 ----------
__global__ void __launch_bounds__(256) k_gemm_fc(
    const unsigned short* __restrict__ convb, const unsigned short* __restrict__ fcWb,
    float* __restrict__ ypart) {
  __shared__ unsigned short lA[128 * 104];
  __shared__ unsigned short lB[128 * 104];
  int t = threadIdx.x;
  int b0 = blockIdx.x * 128, n0 = blockIdx.y * 128, z = blockIdx.z;
  int s0 = (664 * z) / NZ, s1 = (664 * (z + 1)) / NZ;  // 664 = 63744/96 steps
  int w = t >> 6, lane = t & 63, lm = lane & 15, quad = lane >> 4;
  int mq = (w >> 1) * 64, nq = (w & 1) * 64;
  f32x4 acc[4][4];
#pragma unroll
  for (int mi = 0; mi < 4; mi++)
#pragma unroll
    for (int ni = 0; ni < 4; ni++) acc[mi][ni] = (f32x4){0.f, 0.f, 0.f, 0.f};
  for (int st = s0; st < s1; st++) {
    long kc = (long)st * 96;
    __syncthreads();
#pragma unroll
    for (int i = 0; i < 6; i++) {  // 128 rows * 12 chunks = 1536 = 6*256
      int cc = t + 256 * i;
      int row = cc / 12, c8 = cc % 12;
      *(uint4v*)&lA[row * 104 + c8 * 8] =
          *(const uint4v*)&convb[(long)(b0 + row) * FCLEN + kc + c8 * 8];
      uint4v bv = (uint4v){0u, 0u, 0u, 0u};
      int nr = n0 + row;
      if (nr < DIM) bv = *(const uint4v*)&fcWb[(long)nr * FCLEN + kc + c8 * 8];
      *(uint4v*)&lB[row * 104 + c8 * 8] = bv;
    }
    __syncthreads();
#pragma unroll
    for (int ks = 0; ks < 96; ks += 32) {
      short8 af[4], bfr[4];
#pragma unroll
      for (int i2 = 0; i2 < 4; i2++) {
        af[i2] = *(const short8*)&lA[(mq + i2 * 16 + lm) * 104 + ks + quad * 8];
        bfr[i2] = *(const short8*)&lB[(nq + i2 * 16 + lm) * 104 + ks + quad * 8];
      }
#pragma unroll
      for (int mi = 0; mi < 4; mi++)
#pragma unroll
        for (int ni = 0; ni < 4; ni++)
          acc[mi][ni] = __builtin_amdgcn_mfma_f32_16x16x32_bf16(
              __builtin_bit_cast(bf16x8, af[mi]), __builtin_bit_cast(bf16x8, bfr[ni]),
              acc[mi][ni], 0, 0, 0);
    }
  }
  // write split-K partials (N padded to 256); no atomics
#pragma unroll
  for (int mi = 0; mi < 4; mi++)
#pragma unroll
    for (int ni = 0; ni < 4; ni++)
#pragma unroll
      for (int r = 0; r < 4; r++) {
        int gm = b0 + mq + mi * 16 + quad * 4 + r;
        int gn = n0 + nq + ni * 16 + lm;
        ypart[((long)z * BSZ + gm) * 256 + gn] = acc[mi][ni][r];
      }
}

// ---------- reduce split-K partials + bias -> y[512][200] ----------
__global__ void __launch_bounds__(256) k_yred(
    const float* __restrict__ ypart, const float* __restrict__ bias,
    float* __restrict__ y) {
  int i = blockIdx.x * 256 + threadIdx.x;  // 102400 total
  int m = i / DIM, d = i % DIM;
  float s = bias[d];
#pragma unroll 8
  for (int z = 0; z < NZ; z++) s += ypart[((long)z * BSZ + m) * 256 + d];
  y[(long)m * DIM + d] = s;
}

// ---------- BN2 + tanh -> xtf bf16 in MFMA-fragment order ----------
__global__ void k_bn2(const float* __restrict__ y, const float* __restrict__ g,
                      const float* __restrict__ b, unsigned short* __restrict__ xtf) {
  int d = blockIdx.x, ln = threadIdx.x;
  int ks = d >> 5, quad = (d >> 3) & 3, e = d & 7;
  if (d >= DIM) {
    for (int j = 0; j < 8; j++) {
      int row = ln + 64 * j;
      xtf[((((long)(row >> 4) * 7 + ks) * 64) + quad * 16 + (row & 15)) * 8 + e] = 0;
    }
    return;
  }
  float v[8];
  float s1 = 0.f, s2 = 0.f;
#pragma unroll
  for (int j = 0; j < 8; j++) {
    v[j] = y[(long)(ln + 64 * j) * DIM + d];
    s1 += v[j]; s2 += v[j] * v[j];
  }
  s1 = wredf(s1); s2 = wredf(s2);
  s1 = __shfl(s1, 0, 64); s2 = __shfl(s2, 0, 64);
  float m = s1 / BSZ, var = s2 / BSZ - m * m;
  float a = g[d] * rsqrtf(var + EPSV), c = b[d] - m * a;
#pragma unroll
  for (int j = 0; j < 8; j++) {
    int row = ln + 64 * j;
    xtf[((((long)(row >> 4) * 7 + ks) * 64) + quad * 16 + (row & 15)) * 8 + e] =
        f2bf(tanhf(v[j] * a + c));
  }
}

// ---------- final GEMM: out = sigmoid(xt @ bf16(E)^T), direct-E ----------
// 512-thread blocks (8 waves), grid 1563. Block = full M=512 x N=64: E is
// read ONCE from DRAM chip-wide (8 waves share B fragments via L1).
// B fragments are built in-register from fp32 E (2x f32x4 load + 8 f2bf)
// -- this removes the k_ebf pre-pass (~28 us) for +35 MB fetch (~6 us).
// K-pad: fragments with k0>192 are zeroed (A is zero-padded there too);
// rows >= NENT clamp to row 0 and are never stored.
__global__ void __launch_bounds__(512, 4) k_gemmf(
    const unsigned short* __restrict__ xtf, const float* __restrict__ E,
    float* __restrict__ out) {
  int t = threadIdx.x;
  int w = t >> 6, lane = t & 63, lm = lane & 15, quad = lane >> 4;
  long e0 = (long)blockIdx.x * 64;  // this block's 64-entity stripe
  int m0 = w * 64;                  // this wave's 64 batch rows
  int mtb = w * 4;                  // A fragment-tile base (16-row tiles)
  int brow[4];                      // clamped B row base (fp32 elements)
#pragma unroll
  for (int ni = 0; ni < 4; ni++) {
    long ge = e0 + ni * 16 + lm;
    brow[ni] = (int)((ge < NENT ? ge : (long)(NENT - 1)) * DIM);
  }
  f32x4 acc[4][4];
#pragma unroll
  for (int mi = 0; mi < 4; mi++)
#pragma unroll
    for (int ni = 0; ni < 4; ni++) acc[mi][ni] = (f32x4){0.f, 0.f, 0.f, 0.f};
  const short8 z8 = {0, 0, 0, 0, 0, 0, 0, 0};
#pragma unroll
  for (int kk = 0; kk < 7; kk++) {
    int k0 = kk * 32 + quad * 8;
    bool kval = (k0 <= DIM - 8);  // k0 in {..184, 192} valid; 200/208/216 zero
    int kc = kval ? k0 : 0;
    short8 bfr[4], af[4];
#pragma unroll
    for (int ni = 0; ni < 4; ni++) {
      f32x4 lo = *(const f32x4*)&E[(long)brow[ni] + kc];
      f32x4 hi = *(const f32x4*)&E[(long)brow[ni] + kc + 4];
      short8 pk;
      pk[0] = (short)f2bf(lo[0]); pk[1] = (short)f2bf(lo[1]);
      pk[2] = (short)f2bf(lo[2]); pk[3] = (short)f2bf(lo[3]);
      pk[4] = (short)f2bf(hi[0]); pk[5] = (short)f2bf(hi[1]);
      pk[6] = (short)f2bf(hi[2]); pk[7] = (short)f2bf(hi[3]);
      bfr[ni] = kval ? pk : z8;
    }
#pragma unroll
    for (int mi = 0; mi < 4; mi++)
      af[mi] = *(const short8*)&xtf[(((long)(mtb + mi) * 7 + kk) * 64 + lane) * 8];
#pragma unroll
    for (int mi = 0; mi < 4; mi++)
#pragma unroll
      for (int ni = 0; ni < 4; ni++)
        acc[mi][ni] = __builtin_amdgcn_mfma_f32_16x16x32_bf16(
            __builtin_bit_cast(bf16x8, af[mi]), __builtin_bit_cast(bf16x8, bfr[ni]),
            acc[mi][ni], 0, 0, 0);
  }
#pragma unroll
  for (int mi = 0; mi < 4; mi++)
#pragma unroll
    for (int ni = 0; ni < 4; ni++) {
      long ge = e0 + ni * 16 + lm;
      bool ok = (ge < NENT);
#pragma unroll
      for (int r = 0; r < 4; r++) {
        int gm = m0 + mi * 16 + quad * 4 + r;
        if (ok) {
          float x = acc[mi][ni][r];
          out[(long)gm * NENT + ge] = 1.f / (1.f + __expf(-x));
        }
      }
    }
}

extern "C" void kernel_launch(void* const* d_in, const int* in_sizes, int n_in,
                              void* d_out, int out_size, void* d_ws, size_t ws_size,
                              hipStream_t stream) {
  const float* E = (const float*)d_in[0];
  const float* R = (const float*)d_in[1];
  const float* eW = (const float*)d_in[2];
  const float* fcW = (const float*)d_in[3];
  const float* bn0g = (const float*)d_in[4];
  const float* bn0b = (const float*)d_in[5];
  const float* bn1g = (const float*)d_in[6];
  const float* bn1b = (const float*)d_in[7];
  const float* bn2g = (const float*)d_in[8];
  const float* bn2b = (const float*)d_in[9];
  const int* e1 = (const int*)d_in[10];
  const int* ridx = (const int*)d_in[11];
  float* outp = (float*)d_out;

  char* p = (char*)d_ws;
  size_t off = 0;
  auto alloc = [&](size_t bytes) -> char* {
    char* r = p + off;
    off = (off + bytes + 255) & ~(size_t)255;
    return r;
  };
  float* x1 = (float*)alloc((size_t)BSZ * ODIM * 4);
  unsigned short* convb = (unsigned short*)alloc((size_t)BSZ * FCLEN * 2);
  unsigned short* fcWb = (unsigned short*)alloc((size_t)DIM * FCLEN * 2);
  float* ypart = (float*)alloc((size_t)NZ * BSZ * 256 * 4);
  float* y = (float*)alloc((size_t)BSZ * DIM * 4);
  unsigned short* xtf = (unsigned short*)alloc((size_t)BSZ * KPAD * 2);
  float* bn0A = (float*)alloc(DIM * 4);
  float* bn0B = (float*)alloc(DIM * 4);
  float* part = (float*)alloc((size_t)BSZ * 64 * 4);
  float* bn1a = (float*)alloc(OCH * 4);
  float* bn1c = (float*)alloc(OCH * 4);
  float* bias = (float*)alloc(DIM * 4);

  k_bn0<<<DIM, 64, 0, stream>>>(E, e1, bn0g, bn0b, bn0A, bn0B, bias);
  k_mm1<<<dim3(32, 16), 256, 0, stream>>>(E, e1, eW, bn0A, bn0B, x1);
  k_conv<<<BSZ, 256, 0, stream>>>(x1, R, ridx, convb, part);
  k_bn1fin<<<1, 256, 0, stream>>>(part, bn1g, bn1b, bn1a, bn1c);
  k_fcw<<<dim3(DIM, OCH), 256, 0, stream>>>(fcW, bn1a, bn1c, fcWb, bias);
  k_gemm_fc<<<dim3(4, 2, NZ), 256, 0, stream>>>(convb, fcWb, ypart);
  k_yred<<<400, 256, 0, stream>>>(ypart, bias, y);
  k_bn2<<<KPAD, 64, 0, stream>>>(y, bn2g, bn2b, xtf);
  k_gemmf<<<1563, 512, 0, stream>>>(xtf, E, outp);
}